// Round 7
// baseline (294.232 us; speedup 1.0000x reference)
//
#include <hip/hip_runtime.h>
#include <utility>

// Sparse Clebsch-Gordan tensor product, LMAX=3.
// out[b, mu3[k], c] += cg[k] * x[b, mu1[k], c] * y[b, mu2[k], c]
// B=1024, D_IN=16, D_OUT=156, C=128, K~1260 terms.
//
// R6 lesson: dur pinned ~110-113 across all single-pass structures; R5's
// marginal pass = 18 us vs 15.7 us BW floor (~88%). Remaining controllable
// cost: the 2-dispatch gather->ws->main serialization (+~15 us vs R1's
// 1-dispatch overhead) and first-iteration ramp. R7: single dispatch, cg read
// directly via compile-time scattered offsets (R2-proven equal speed); all 32
// x/y loads hoisted before the octant loop (one wait, then pure FMA+store);
// octant-pair order staggered by blockIdx to desync store phases.

#define D_IN_ 16
#define D_OUT_ 156
#define C_ 128
#define KMAX_ 2048

struct CGRows {
    int n;
    int start[D_OUT_ + 1];  // row start offsets
    int k[KMAX_];           // original term index into cg[]
    int m1[KMAX_];
    int m2[KMAX_];
};

constexpr CGRows build_rows() {
    int mu1[KMAX_] = {}, mu2[KMAX_] = {}, mu3[KMAX_] = {};
    int n = 0;
    const int off_in[4] = {0, 1, 4, 9};
    int off3 = 0;
    for (int l1 = 0; l1 <= 3; ++l1) {
        for (int l2 = 0; l2 <= 3; ++l2) {
            int lo = l1 > l2 ? l1 - l2 : l2 - l1;
            int hi = (l1 + l2) < 3 ? (l1 + l2) : 3;
            for (int l3 = lo; l3 <= hi; ++l3) {
                for (int m1 = 0; m1 < 2 * l1 + 1; ++m1) {
                    for (int m2 = 0; m2 < 2 * l2 + 1; ++m2) {
                        int a = m1 - l1, b = m2 - l2;
                        for (int m3 = 0; m3 < 2 * l3 + 1; ++m3) {
                            int c = m3 - l3;
                            int s = a + b; if (s < 0) s = -s;
                            int d = a - b; if (d < 0) d = -d;
                            int e = c < 0 ? -c : c;
                            if (s == e || d == e) {
                                mu1[n] = off_in[l1] + m1;
                                mu2[n] = off_in[l2] + m2;
                                mu3[n] = off3 + m3;
                                ++n;
                            }
                        }
                    }
                }
                off3 += 2 * l3 + 1;
            }
        }
    }
    CGRows r{};
    r.n = n;
    int cnt[D_OUT_] = {};
    for (int i = 0; i < n; ++i) cnt[mu3[i]]++;
    r.start[0] = 0;
    for (int j = 0; j < D_OUT_; ++j) r.start[j + 1] = r.start[j] + cnt[j];
    int pos[D_OUT_] = {};
    for (int j = 0; j < D_OUT_; ++j) pos[j] = r.start[j];
    for (int i = 0; i < n; ++i) {
        int j = mu3[i];
        int p = pos[j]++;
        r.k[p] = i;
        r.m1[p] = mu1[i];
        r.m2[p] = mu2[i];
    }
    return r;
}

constexpr CGRows CG = build_rows();
constexpr int K = CG.n;
static_assert(K <= KMAX_, "KMAX too small");

// Term-balanced octant row boundaries.
constexpr int findo(int i) {
    int target = (CG.n * i) / 8;
    int j = 0;
    while (CG.start[j] < target) ++j;
    return j;
}
constexpr int OBND[9] = {0, findo(1), findo(2), findo(3), findo(4),
                         findo(5), findo(6), findo(7), D_OUT_};

template <int... Is>
__device__ __forceinline__ void load_all(float (&v)[D_IN_], const float* __restrict__ base,
                                         std::integer_sequence<int, Is...>) {
    ((v[Is] = base[Is * C_]), ...);
}

template <int Base, int... Ts>
__device__ __forceinline__ float row_sum(const float* __restrict__ cg,
                                         const float (&xv)[D_IN_],
                                         const float (&yv)[D_IN_],
                                         std::integer_sequence<int, Ts...>) {
    float s = 0.0f;
    ((s = fmaf(cg[CG.k[Base + Ts]], xv[CG.m1[Base + Ts]] * yv[CG.m2[Base + Ts]], s)), ...);
    return s;
}

template <int J>
__device__ __forceinline__ void store_row(float* __restrict__ ob, const float* __restrict__ cg,
                                          const float (&xv)[D_IN_], const float (&yv)[D_IN_]) {
    constexpr int base = CG.start[J];
    constexpr int nt = CG.start[J + 1] - CG.start[J];
    ob[J * C_] = row_sum<base>(cg, xv, yv, std::make_integer_sequence<int, nt>{});
}

template <int J0, int... Js>
__device__ __forceinline__ void rows_range(float* __restrict__ ob, const float* __restrict__ cg,
                                           const float (&xv)[D_IN_], const float (&yv)[D_IN_],
                                           std::integer_sequence<int, Js...>) {
    (store_row<J0 + Js>(ob, cg, xv, yv), ...);
}

template <int O>
__device__ __forceinline__ void do_octant(float* __restrict__ ob, const float* __restrict__ cg,
                                          const float (&xv)[D_IN_], const float (&yv)[D_IN_]) {
    rows_range<OBND[O]>(ob, cg, xv, yv,
                        std::make_integer_sequence<int, OBND[O + 1] - OBND[O]>{});
}

__global__ __launch_bounds__(256, 4) void tp_cg_kernel(
    const float* __restrict__ x, const float* __restrict__ y,
    const float* __restrict__ cg, float* __restrict__ out) {
    const int tid = (int)threadIdx.x;
    const int c = tid & (C_ - 1);
    const int qhalf = tid >> 7;  // wave-uniform: which octant of each pair
    const int b = (int)blockIdx.x;

    const float* xb = x + (size_t)b * (D_IN_ * C_) + c;
    const float* yb = y + (size_t)b * (D_IN_ * C_) + c;
    float* ob = out + (size_t)b * (D_OUT_ * C_) + c;

    // One load phase: all 16 rows of x and y for this b (one vmcnt wait),
    // then 4 octant-pair iterations of pure FMA+store from registers.
    float xv[D_IN_], yv[D_IN_];
    load_all(xv, xb, std::make_integer_sequence<int, D_IN_>{});
    load_all(yv, yb, std::make_integer_sequence<int, D_IN_>{});

#pragma unroll 1
    for (int i = 0; i < 4; ++i) {
        const int p = (i + b) & 3;             // stagger store phases per block
        const int oct = (p << 1) | qhalf;      // wave-uniform octant id
        switch (oct) {
            case 0: do_octant<0>(ob, cg, xv, yv); break;
            case 1: do_octant<1>(ob, cg, xv, yv); break;
            case 2: do_octant<2>(ob, cg, xv, yv); break;
            case 3: do_octant<3>(ob, cg, xv, yv); break;
            case 4: do_octant<4>(ob, cg, xv, yv); break;
            case 5: do_octant<5>(ob, cg, xv, yv); break;
            case 6: do_octant<6>(ob, cg, xv, yv); break;
            default: do_octant<7>(ob, cg, xv, yv); break;
        }
    }
}

extern "C" void kernel_launch(void* const* d_in, const int* in_sizes, int n_in,
                              void* d_out, int out_size, void* d_ws, size_t ws_size,
                              hipStream_t stream) {
    const float* x  = (const float*)d_in[0];
    const float* y  = (const float*)d_in[1];
    const float* cg = (const float*)d_in[2];
    float* out = (float*)d_out;

    const int B = in_sizes[0] / (D_IN_ * C_);

    // Single dispatch: one block per batch b.
    tp_cg_kernel<<<B, 256, 0, stream>>>(x, y, cg, out);
}

// Round 8
// 109.158 us; speedup vs baseline: 2.6955x; 2.6955x over previous
//
#include <hip/hip_runtime.h>
#include <utility>

// Sparse Clebsch-Gordan tensor product, LMAX=3.
// out[b, mu3[k], c] += cg[k] * x[b, mu1[k], c] * y[b, mu2[k], c]
// B=1024, D_IN=16, D_OUT=156, C=128, K~1260 terms.
//
// R7 lesson: runtime-indexed switch-in-loop over fat unrolled bodies ->
// register-allocator spill to scratch (WRITE 573 MB = 7x output, kernel 212us).
// Unrolled bodies must be reached by wave-uniform BRANCHES only.
// R8 = R3 structure exactly (best: 109.5us) minus the gather dispatch:
// direct scattered cg[CG.k[...]] reads (R2-proven free), single dispatch,
// float2 lanes, 2-way term-balanced row split, no loops. Steady-state pass
// is ~18us vs 15.7us BW floor (~88%); remaining dur is fixed harness cost.

#define D_IN_ 16
#define D_OUT_ 156
#define C_ 128
#define KMAX_ 2048

struct CGRows {
    int n;
    int start[D_OUT_ + 1];  // row start offsets
    int k[KMAX_];           // original term index into cg[]
    int m1[KMAX_];
    int m2[KMAX_];
};

constexpr CGRows build_rows() {
    int mu1[KMAX_] = {}, mu2[KMAX_] = {}, mu3[KMAX_] = {};
    int n = 0;
    const int off_in[4] = {0, 1, 4, 9};
    int off3 = 0;
    for (int l1 = 0; l1 <= 3; ++l1) {
        for (int l2 = 0; l2 <= 3; ++l2) {
            int lo = l1 > l2 ? l1 - l2 : l2 - l1;
            int hi = (l1 + l2) < 3 ? (l1 + l2) : 3;
            for (int l3 = lo; l3 <= hi; ++l3) {
                for (int m1 = 0; m1 < 2 * l1 + 1; ++m1) {
                    for (int m2 = 0; m2 < 2 * l2 + 1; ++m2) {
                        int a = m1 - l1, b = m2 - l2;
                        for (int m3 = 0; m3 < 2 * l3 + 1; ++m3) {
                            int c = m3 - l3;
                            int s = a + b; if (s < 0) s = -s;
                            int d = a - b; if (d < 0) d = -d;
                            int e = c < 0 ? -c : c;
                            if (s == e || d == e) {
                                mu1[n] = off_in[l1] + m1;
                                mu2[n] = off_in[l2] + m2;
                                mu3[n] = off3 + m3;
                                ++n;
                            }
                        }
                    }
                }
                off3 += 2 * l3 + 1;
            }
        }
    }
    CGRows r{};
    r.n = n;
    int cnt[D_OUT_] = {};
    for (int i = 0; i < n; ++i) cnt[mu3[i]]++;
    r.start[0] = 0;
    for (int j = 0; j < D_OUT_; ++j) r.start[j + 1] = r.start[j] + cnt[j];
    int pos[D_OUT_] = {};
    for (int j = 0; j < D_OUT_; ++j) pos[j] = r.start[j];
    for (int i = 0; i < n; ++i) {
        int j = mu3[i];
        int p = pos[j]++;
        r.k[p] = i;
        r.m1[p] = mu1[i];
        r.m2[p] = mu2[i];
    }
    return r;
}

constexpr CGRows CG = build_rows();
constexpr int K = CG.n;
static_assert(K <= KMAX_, "KMAX too small");

// Row split point: first row index whose start offset reaches half the terms.
constexpr int find_split() {
    int j = 0;
    while (CG.start[j] < CG.n / 2) ++j;
    return j;
}
constexpr int RSPLIT = find_split();

constexpr unsigned need1(int j0, int j1) {
    unsigned m = 0;
    for (int p = CG.start[j0]; p < CG.start[j1]; ++p) m |= 1u << CG.m1[p];
    return m;
}
constexpr unsigned need2(int j0, int j1) {
    unsigned m = 0;
    for (int p = CG.start[j0]; p < CG.start[j1]; ++p) m |= 1u << CG.m2[p];
    return m;
}

template <unsigned M, int I>
__device__ __forceinline__ void load1(float2 (&v)[D_IN_], const float* __restrict__ base) {
    if constexpr ((M >> I) & 1u) v[I] = *(const float2*)(base + I * C_);
    else v[I] = make_float2(0.0f, 0.0f);
}

template <unsigned M, int... Is>
__device__ __forceinline__ void load_masked(float2 (&v)[D_IN_], const float* __restrict__ base,
                                            std::integer_sequence<int, Is...>) {
    (load1<M, Is>(v, base), ...);
}

template <int Base, int... Ts>
__device__ __forceinline__ float2 row_sum2(const float* __restrict__ cg,
                                           const float2 (&xv)[D_IN_],
                                           const float2 (&yv)[D_IN_],
                                           std::integer_sequence<int, Ts...>) {
    float2 s = make_float2(0.0f, 0.0f);
    (((s.x = fmaf(cg[CG.k[Base + Ts]], xv[CG.m1[Base + Ts]].x * yv[CG.m2[Base + Ts]].x, s.x)),
      (s.y = fmaf(cg[CG.k[Base + Ts]], xv[CG.m1[Base + Ts]].y * yv[CG.m2[Base + Ts]].y, s.y))), ...);
    return s;
}

template <int J>
__device__ __forceinline__ void store_row(float* __restrict__ ob, const float* __restrict__ cg,
                                          const float2 (&xv)[D_IN_], const float2 (&yv)[D_IN_]) {
    constexpr int base = CG.start[J];
    constexpr int nt = CG.start[J + 1] - CG.start[J];
    float2 s = row_sum2<base>(cg, xv, yv, std::make_integer_sequence<int, nt>{});
    *(float2*)(ob + J * C_) = s;
}

template <int J0, int... Js>
__device__ __forceinline__ void rows_range(float* __restrict__ ob, const float* __restrict__ cg,
                                           const float2 (&xv)[D_IN_], const float2 (&yv)[D_IN_],
                                           std::integer_sequence<int, Js...>) {
    (store_row<J0 + Js>(ob, cg, xv, yv), ...);
}

__global__ __launch_bounds__(256, 2) void tp_cg_kernel(
    const float* __restrict__ x, const float* __restrict__ y,
    const float* __restrict__ cg, float* __restrict__ out) {
    const int tid = (int)threadIdx.x;
    const int c2 = tid & 63;             // float2 column index (64 per row)
    const int half = (tid >> 6) & 1;     // wave-uniform row-range selector
    const int b = (int)((blockIdx.x << 1) | (tid >> 7));

    const float* xb = x + (size_t)b * (D_IN_ * C_) + c2 * 2;
    const float* yb = y + (size_t)b * (D_IN_ * C_) + c2 * 2;
    float* ob = out + (size_t)b * (D_OUT_ * C_) + c2 * 2;

    float2 xv[D_IN_], yv[D_IN_];
    if (half == 0) {
        constexpr unsigned m1 = need1(0, RSPLIT), m2 = need2(0, RSPLIT);
        load_masked<m1>(xv, xb, std::make_integer_sequence<int, D_IN_>{});
        load_masked<m2>(yv, yb, std::make_integer_sequence<int, D_IN_>{});
        rows_range<0>(ob, cg, xv, yv, std::make_integer_sequence<int, RSPLIT>{});
    } else {
        constexpr unsigned m1 = need1(RSPLIT, D_OUT_), m2 = need2(RSPLIT, D_OUT_);
        load_masked<m1>(xv, xb, std::make_integer_sequence<int, D_IN_>{});
        load_masked<m2>(yv, yb, std::make_integer_sequence<int, D_IN_>{});
        rows_range<RSPLIT>(ob, cg, xv, yv, std::make_integer_sequence<int, D_OUT_ - RSPLIT>{});
    }
}

extern "C" void kernel_launch(void* const* d_in, const int* in_sizes, int n_in,
                              void* d_out, int out_size, void* d_ws, size_t ws_size,
                              hipStream_t stream) {
    const float* x  = (const float*)d_in[0];
    const float* y  = (const float*)d_in[1];
    const float* cg = (const float*)d_in[2];
    float* out = (float*)d_out;

    const int B = in_sizes[0] / (D_IN_ * C_);

    // Single dispatch: 2 batch rows per 256-thread block.
    tp_cg_kernel<<<B / 2, 256, 0, stream>>>(x, y, cg, out);
}